// Round 4
// baseline (230.948 us; speedup 1.0000x reference)
//
#include <hip/hip_runtime.h>

// Problem constants
#define BATCH 4
#define SEQ   2048
#define DIM   1024
#define MTOT  (BATCH * SEQ)   // 8192
#define BK    32              // k-tile depth for the legacy 128x128 core

typedef __bf16 bf16x8 __attribute__((ext_vector_type(8)));
typedef __bf16 bf16x4 __attribute__((ext_vector_type(4)));
typedef float  f32x4  __attribute__((ext_vector_type(4)));

#define VMCNT(N) asm volatile("s_waitcnt vmcnt(" #N ")" ::: "memory")

// Async global->LDS, 16B per lane.
__device__ __forceinline__ void gl_lds16(const __bf16* g, __bf16* l) {
    __builtin_amdgcn_global_load_lds(
        (const __attribute__((address_space(1))) void*)g,
        (__attribute__((address_space(3))) void*)l,
        16, 0, 0);
}

// ---------------------------------------------------------------------------
// K0: fused fp32 -> bf16 conversion for x, Wq, Wk, Wv in ONE launch.
// Blocks 5632..5639 zero the row-sum accumulator (8192 f32).
__global__ __launch_bounds__(256) void cvt_all_kernel(
    const float* __restrict__ x,  const float* __restrict__ w0,
    const float* __restrict__ w1, const float* __restrict__ w2,
    __bf16* __restrict__ xd, __bf16* __restrict__ d0,
    __bf16* __restrict__ d1, __bf16* __restrict__ d2,
    float* __restrict__ sums)
{
    const int bid = blockIdx.x;
    if (bid >= 5632) {
        const int i = ((bid - 5632) * 256 + threadIdx.x) * 4;
        *(float4*)(sums + i) = (float4){0.f, 0.f, 0.f, 0.f};
        return;
    }
    const float* s;
    __bf16* d;
    int base;
    if (bid < 4096)      { s = x;  d = xd; base = bid; }
    else if (bid < 4608) { s = w0; d = d0; base = bid - 4096; }
    else if (bid < 5120) { s = w1; d = d1; base = bid - 4608; }
    else                 { s = w2; d = d2; base = bid - 5120; }
    const int i = (base * 256 + threadIdx.x) * 8;
    const float4 a = *(const float4*)(s + i);
    const float4 b = *(const float4*)(s + i + 4);
    bf16x8 o;
    o[0] = (__bf16)a.x; o[1] = (__bf16)a.y; o[2] = (__bf16)a.z; o[3] = (__bf16)a.w;
    o[4] = (__bf16)b.x; o[5] = (__bf16)b.y; o[6] = (__bf16)b.z; o[7] = (__bf16)b.w;
    *(bf16x8*)(d + i) = o;
}

// ---------------------------------------------------------------------------
// Legacy 128x128 bf16 GEMM core (m97 structure) — still used by scores/pv.
__device__ __forceinline__ void gemm_core(
    const __bf16* __restrict__ A, size_t lda,
    const __bf16* __restrict__ Bm, size_t ldb,
    int m0, int n0, int kTiles,
    __bf16* lA, __bf16* lB,
    f32x4 (&acc)[4][4])
{
    const int tid  = threadIdx.x;
    const int lane = tid & 63;
    const int wave = tid >> 6;
    const int wm = (wave >> 1) << 6;
    const int wn = (wave & 1) << 6;

#pragma unroll
    for (int i = 0; i < 4; ++i)
#pragma unroll
        for (int j = 0; j < 4; ++j)
            acc[i][j] = (f32x4){0.f, 0.f, 0.f, 0.f};

    for (int kt = 0; kt < kTiles; ++kt) {
        const int k0 = kt << 5;
        __syncthreads();
#pragma unroll
        for (int it = 0; it < 2; ++it) {
            const int f   = tid + (it << 8);
            const int row = f >> 2;
            const int col = (f & 3) << 3;
            gl_lds16(A  + (size_t)(m0 + row) * lda + (size_t)(k0 + col), lA + f * 8);
            gl_lds16(Bm + (size_t)(n0 + row) * ldb + (size_t)(k0 + col), lB + f * 8);
        }
        __syncthreads();

        bf16x8 af[4], bfr[4];
#pragma unroll
        for (int i = 0; i < 4; ++i) {
            af[i]  = *(const bf16x8*)(lA + (size_t)(wm + i * 16 + (lane & 15)) * BK + ((lane >> 4) << 3));
            bfr[i] = *(const bf16x8*)(lB + (size_t)(wn + i * 16 + (lane & 15)) * BK + ((lane >> 4) << 3));
        }
#pragma unroll
        for (int i = 0; i < 4; ++i)
#pragma unroll
            for (int j = 0; j < 4; ++j)
                acc[i][j] = __builtin_amdgcn_mfma_f32_16x16x32_bf16(af[i], bfr[j], acc[i][j], 0, 0, 0);
    }
}

// Epilogue for the legacy core (scores/pv): C-tile -> LDS scratch -> coalesced
// bf16x8 stores. expMask: store exp(val*scale), causal-masked on diag tiles.
// sums!=nullptr: accumulate per-row sums of the STORED (bf16-rounded) values
// via 16-lane shfl reduce + one f32 atomicAdd per row per wave.
__device__ __forceinline__ void store_tile_bf16(
    f32x4 (&acc)[4][4], __bf16* scratch, bool transpose, float scale,
    __bf16* dst, size_t ldo, size_t r0, size_t c0,
    bool expMask = false, bool diag = false, float* sums = nullptr)
{
    const int tid  = threadIdx.x;
    const int lane = tid & 63;
    const int wave = tid >> 6;
    const int wm = (wave >> 1) << 6, wn = (wave & 1) << 6;
    const int quad = lane >> 4;
    const int ln15 = lane & 15;

#pragma unroll
    for (int p = 0; p < 4; ++p) {
        __syncthreads();
        if (!transpose) {
            if (wm == ((p >> 1) << 6)) {
#pragma unroll
                for (int ih = 0; ih < 2; ++ih) {
                    const int i = ((p & 1) << 1) + ih;
                    const int lr = ih * 16 + quad * 4;
#pragma unroll
                    for (int r = 0; r < 4; ++r) {
                        const int lm = wm + ((p & 1) << 5) + lr + r;
                        float ps = 0.f;
#pragma unroll
                        for (int j = 0; j < 4; ++j) {
                            const int ln = wn + j * 16 + ln15;
                            float v = acc[i][j][r] * scale;
                            if (expMask) {
                                v = (!diag || ln <= lm) ? __expf(v) : 0.f;
                            }
                            const __bf16 vb = (__bf16)v;
                            scratch[(lr + r) * 136 + ln] = vb;
                            ps += (float)vb;
                        }
                        if (sums) {
#pragma unroll
                            for (int off = 1; off < 16; off <<= 1)
                                ps += __shfl_xor(ps, off);
                            if (ln15 == 0)
                                atomicAdd(&sums[r0 + (p << 5) + lr + r], ps);
                        }
                    }
                }
            }
        } else {
            if (wn == ((p >> 1) << 6)) {
#pragma unroll
                for (int jh = 0; jh < 2; ++jh) {
                    const int j = ((p & 1) << 1) + jh;
                    const int lr = jh * 16 + ln15;
#pragma unroll
                    for (int i = 0; i < 4; ++i)
#pragma unroll
                        for (int r = 0; r < 4; ++r)
                            scratch[lr * 136 + wm + i * 16 + quad * 4 + r] =
                                (__bf16)(acc[i][j][r] * scale);
                }
            }
        }
        __syncthreads();
#pragma unroll
        for (int it = 0; it < 2; ++it) {
            const int g   = tid + (it << 8);
            const int row = g >> 4;
            const int col = (g & 15) << 3;
            *(bf16x8*)(dst + (r0 + p * 32 + row) * ldo + c0 + col) =
                *(const bf16x8*)(scratch + row * 136 + col);
        }
    }
}

// ---------------------------------------------------------------------------
// K1 v4: QKV — 256 blocks x 3 sequential 256x128 units (shared A-panel).
// Changes vs round 3 (counters: MfmaUtil 31%, LDS-read-bound):
//   - Wave grid 4M x 2N (wave = 64x64, acc[4][4]): A-read redundancy x2
//     (was x4) -> CU ds_read volume 160->128 KB per K-tile. Each wave reads
//     exactly ONE A-half (wm>>1) and ONE B-half (wn).
//   - One-phase-ahead ds_read pipeline: MFMA group G_j = all 4 m-frags x
//     bF[j] x 2 ksub (8 MFMAs). bF[j+1] is read during phase j; aF+bF0 of
//     tile T+1 are read during P2/P3 of tile T (aF double-buffered via
//     2-tile loop unroll, static names). LDS service overlaps prior MFMA.
//   - vmcnt seals (steady): P1=4 (A(T+1) landed, for P2's aF reads);
//     P2=5 (B0(T+1), for P3's bF0 read); P3=4 (B1(T+1), for next P0's bF1).
//     Tails: T+2>=nt -> 2/1/0; T+1>=nt -> none. Stage->overwrite ledger:
//     A(T+2)@P1,P2 overwrite slots sealed at P0's closing barrier;
//     B(T+1)@P0,P1 overwrite slots sealed at P3(T-1)'s closing barrier.
//   - LDS 96 KiB: dbuf x (A 256x64 + B 128x64); rotation swizzle unchanged.
__global__ __launch_bounds__(512, 2) void qkv_kernel(
    const __bf16* __restrict__ x,
    const __bf16* __restrict__ Wq,
    const __bf16* __restrict__ Wk,
    const __bf16* __restrict__ Wv,
    __bf16* __restrict__ Q, __bf16* __restrict__ Kb, __bf16* __restrict__ Vt)
{
    __shared__ __bf16 smem[49152];   // 96 KiB

    const int L  = blockIdx.x;
    const int g  = (L & 7) * 32 + (L >> 3);   // bijective XCD swizzle (256=8*32)
    const int m0 = (g >> 3) << 8;             // 32 m-panels of 256 rows
    const int B3 = g & 7;                     // unit-triple within the panel

    const int tid  = threadIdx.x;
    const int lane = tid & 63;
    const int ln15 = lane & 15;
    const int quad = lane >> 4;
    const int wave = tid >> 6;
    const int wm   = wave >> 1;        // 0..3 (M): wave rows wm*64..wm*64+63
    const int wn   = wave & 1;         // 0..1 (N): wave cols wn*64..wn*64+63

    // Staging: LDS dest linear; global source column carries the INVERSE
    // rotation so the rotated ds_read returns the right element.
    const int r0  = tid >> 3;                                   // dest row 0..63
    const int cst = ((((tid & 7) + 8) - (r0 & 7)) & 7) << 3;    // element col
    // Fragment read: phys col = (ksub*32 + quad*8 + (row&7)*8) & 63;
    // row&7 == ln15&7; ksub1 address = ksub0 ^ 32.
    const int cq  = (((quad << 3) + ((ln15 & 7) << 3)) & 63);

    // A: half (wm>>1) at elem base (wm>>1)*8192; local row (wm&1)*64+i*16+ln15.
    int aoff[4];
#pragma unroll
    for (int i = 0; i < 4; ++i)
        aoff[i] = ((wm >> 1) ? 8192 : 0) + (((wm & 1) << 6) + i * 16 + ln15) * 64 + cq;
    // B: half wn at 16384 + wn*4096; local row j*16+ln15.
    int boff[4];
#pragma unroll
    for (int j = 0; j < 4; ++j)
        boff[j] = 16384 + (wn ? 4096 : 0) + (j * 16 + ln15) * 64 + cq;

    const __bf16* Ab = x + (size_t)m0 * DIM;
    constexpr int nt = DIM / 64;   // 16 K-tiles (even)

    for (int uu = 0; uu < 3; ++uu) {
        const int u  = B3 * 3 + uu;
        const int z  = u >> 3;             // 0=Q, 1=K, 2=V
        const int n0 = (u & 7) << 7;
        const __bf16* W  = (z == 0) ? Wq : (z == 1) ? Wk : Wv;
        const __bf16* Bb = W + (size_t)n0 * DIM;

        f32x4 acc[4][4];
#pragma unroll
        for (int i = 0; i < 4; ++i)
#pragma unroll
            for (int j = 0; j < 4; ++j) acc[i][j] = (f32x4){0.f, 0.f, 0.f, 0.f};

        // LDS per buf (elems): A0@0, A1@8192, B0@16384, B1@20480; stride 24576.
#define SA(h, t) do {                                                         \
    const __bf16* gs_ = Ab + (size_t)((h) * 128 + r0) * DIM + ((t) << 6) + cst; \
    __bf16* ls_ = smem + (((t) & 1) * 24576 + (h) * 8192) + tid * 8;          \
    gl_lds16(gs_, ls_);                                                       \
    gl_lds16(gs_ + (size_t)64 * DIM, ls_ + 4096); } while (0)
#define SB(h, t) do {                                                         \
    const __bf16* gs_ = Bb + (size_t)((h) * 64 + r0) * DIM + ((t) << 6) + cst; \
    __bf16* ls_ = smem + (((t) & 1) * 24576 + 16384 + (h) * 4096) + tid * 8;  \
    gl_lds16(gs_, ls_); } while (0)

        bf16x8 aFa[4][2], aFb[4][2], bFr[2][2];   // bFr[set][ksub]
#define LDA_LO(DST, t) do { const __bf16* p_ = smem + ((t) & 1) * 24576;      \
    DST[0][0] = *(const bf16x8*)(p_ + aoff[0]);                               \
    DST[0][1] = *(const bf16x8*)(p_ + (aoff[0] ^ 32));                        \
    DST[1][0] = *(const bf16x8*)(p_ + aoff[1]);                               \
    DST[1][1] = *(const bf16x8*)(p_ + (aoff[1] ^ 32)); } while (0)
#define LDA_HI(DST, t) do { const __bf16* p_ = smem + ((t) & 1) * 24576;      \
    DST[2][0] = *(const bf16x8*)(p_ + aoff[2]);                               \
    DST[2][1] = *(const bf16x8*)(p_ + (aoff[2] ^ 32));                        \
    DST[3][0] = *(const bf16x8*)(p_ + aoff[3]);                               \
    DST[3][1] = *(const bf16x8*)(p_ + (aoff[3] ^ 32)); } while (0)
#define LDB(s, j, t) do { const __bf16* p_ = smem + ((t) & 1) * 24576;        \
    bFr[s][0] = *(const bf16x8*)(p_ + boff[j]);                               \
    bFr[s][1] = *(const bf16x8*)(p_ + (boff[j] ^ 32)); } while (0)
#define MG(j, s, AC) do {                                                     \
    __builtin_amdgcn_s_setprio(1);                                            \
    _Pragma("unroll") for (int i_ = 0; i_ < 4; ++i_) {                        \
        acc[i_][j] = __builtin_amdgcn_mfma_f32_16x16x32_bf16(                 \
            AC[i_][0], bFr[s][0], acc[i_][j], 0, 0, 0);                       \
        acc[i_][j] = __builtin_amdgcn_mfma_f32_16x16x32_bf16(                 \
            AC[i_][1], bFr[s][1], acc[i_][j], 0, 0, 0); }                     \
    __builtin_amdgcn_s_setprio(0); } while (0)

        // One tile: 4 phases. AC = current aF set, AN = next (loaded here).
#define TILE(AC, AN, T) do {                                                  \
    /* P0: MFMA G0(set0); read bF1->set1; stage B0(T+1). */                   \
    LDB(1, 1, T);                                                             \
    if ((T) + 1 < nt) SB(0, (T) + 1);                                         \
    __builtin_amdgcn_s_barrier();                                             \
    MG(0, 0, AC);                                                             \
    __builtin_amdgcn_s_barrier();                                             \
    /* P1: G1(set1); read bF2->set0; stage B1(T+1), A0(T+2); seal A(T+1). */  \
    LDB(0, 2, T);                                                             \
    if ((T) + 1 < nt) SB(1, (T) + 1);                                         \
    if ((T) + 2 < nt) SA(0, (T) + 2);                                         \
    if ((T) + 1 < nt) { if ((T) + 2 < nt) VMCNT(4); else VMCNT(2); }          \
    __builtin_amdgcn_s_barrier();                                             \
    MG(1, 1, AC);                                                             \
    __builtin_amdgcn_s_barrier();                                             \
    /* P2: G2(set0); read bF3->set1 + aF(T+1) lo; stage A1(T+2); seal B0. */  \
    LDB(1, 3, T);                                                             \
    if ((T) + 1 < nt) LDA_LO(AN, (T) + 1);                                    \
    if ((T) + 2 < nt) SA(1, (T) + 2);                                         \
    if ((T) + 1 < nt) { if ((T) + 2 < nt) VMCNT(5); else VMCNT(1); }          \
    __builtin_amdgcn_s_barrier();                                             \
    MG(2, 0, AC);                                                             \
    __builtin_amdgcn_s_barrier();                                             \
    /* P3: G3(set1); read aF(T+1) hi + bF0(T+1)->set0; seal B1(T+1). */       \
    if ((T) + 1 < nt) { LDA_HI(AN, (T) + 1); LDB(0, 0, (T) + 1); }            \
    if ((T) + 1 < nt) { if ((T) + 2 < nt) VMCNT(4); else VMCNT(0); }          \
    __builtin_amdgcn_s_barrier();                                             \
    MG(3, 1, AC);                                                             \
    __builtin_amdgcn_s_barrier(); } while (0)

        // Prologue: stage tile0 + A(1); seal tile0; prime aF(0)+bF0(0).
        SA(0, 0); SA(1, 0); SB(0, 0); SB(1, 0);
        SA(0, 1); SA(1, 1);
        VMCNT(4);                    // tile0 landed; A(1)'s 4 insts outstanding
        __builtin_amdgcn_s_barrier();
        LDA_LO(aFa, 0); LDA_HI(aFa, 0); LDB(0, 0, 0);

#pragma unroll 1
        for (int T = 0; T < nt; T += 2) {
            TILE(aFa, aFb, T);
            TILE(aFb, aFa, T + 1);
        }
#undef SA
#undef SB
#undef LDA_LO
#undef LDA_HI
#undef LDB
#undef MG
#undef TILE

        // ---------------- epilogue ----------------
        __syncthreads();
        __bf16* scratch = smem;

        if (z < 2) {
            __bf16* dst = (z == 0) ? Q : Kb;
#pragma unroll
            for (int h = 0; h < 2; ++h) {     // slab: C rows h*128..h*128+127
                if ((wm >> 1) == h) {
#pragma unroll
                    for (int i = 0; i < 4; ++i) {
                        const int lr = ((wm & 1) << 6) + i * 16 + quad * 4;
#pragma unroll
                        for (int j = 0; j < 4; ++j) {
                            const int lc = (wn << 6) + j * 16 + ln15;
#pragma unroll
                            for (int r = 0; r < 4; ++r)
                                scratch[(lr + r) * 136 + lc] = (__bf16)acc[i][j][r];
                        }
                    }
                }
                __syncthreads();
#pragma unroll
                for (int it = 0; it < 4; ++it) {
                    const int f = tid + (it << 9);
                    const int row = f >> 4, col = (f & 15) << 3;
                    *(bf16x8*)(dst + (size_t)(m0 + h * 128 + row) * DIM + n0 + col) =
                        *(const bf16x8*)(scratch + row * 136 + col);
                }
                __syncthreads();
            }
        } else {
            // V transposed: Vt[b][d][s]; scratch[d 128][s 256], stride 264.
            const size_t b  = (size_t)(m0 >> 11);
            const int  ms0  = m0 & (SEQ - 1);
            __bf16* dst = Vt + b * (size_t)DIM * SEQ;
#pragma unroll
            for (int i = 0; i < 4; ++i) {
                const int sl = (wm << 6) + i * 16 + quad * 4;   // s-local 0..255
#pragma unroll
                for (int j = 0; j < 4; ++j) {
                    const int dl = (wn << 6) + j * 16 + ln15;    // d-local 0..127
                    bf16x4 v;
#pragma unroll
                    for (int r = 0; r < 4; ++r) v[r] = (__bf16)acc[i][j][r];
                    *(bf16x4*)(scratch + dl * 264 + sl) = v;
                }
            }
            __syncthreads();
#pragma unroll
            for (int it = 0; it < 8; ++it) {
                const int f = tid + (it << 9);
                const int row = f >> 5, blk = f & 31;
                *(bf16x8*)(dst + (size_t)(n0 + row) * SEQ + ms0 + blk * 8) =
                    *(const bf16x8*)(scratch + row * 264 + blk * 8);
            }
            __syncthreads();
        }
    }
}

// ---------------------------------------------------------------------------
// K2: Sc[b] = exp( Q[b]·K[b]^T / 32 ), UNNORMALIZED, causal-masked on the
// diagonal tile; also accumulates per-row sums (fused rowsum). Tri-packed
// 544 blocks; XCD swizzle.
__global__ __launch_bounds__(256) void scores_kernel(
    const __bf16* __restrict__ Q, const __bf16* __restrict__ Kb,
    __bf16* __restrict__ Sc, float* __restrict__ sums)
{
    const int L = blockIdx.x;
    const int g = (L & 7) * 68 + (L >> 3);   // 0..543
    const int b = g / 136;
    const int t = g - b * 136;
    int i = (int)((sqrtf(8.f * t + 1.f) - 1.f) * 0.5f);
    while ((i + 1) * (i + 2) / 2 <= t) ++i;
    while (i * (i + 1) / 2 > t) --i;
    const int j = t - i * (i + 1) / 2;

    __shared__ __bf16 smem[8192];
    __bf16* lA = smem;
    __bf16* lB = smem + 128 * BK;
    const __bf16* A  = Q  + (size_t)b * SEQ * DIM;
    const __bf16* Bm = Kb + (size_t)b * SEQ * DIM;

    f32x4 acc[4][4];
    gemm_core(A, DIM, Bm, DIM, i << 7, j << 7, DIM / BK, lA, lB, acc);

    store_tile_bf16(acc, smem, false, 0.03125f,   // 1/sqrt(1024)
                    Sc + (size_t)b * SEQ * SEQ, SEQ,
                    (size_t)(i << 7), (size_t)(j << 7),
                    /*expMask=*/true, /*diag=*/(i == j),
                    sums + (size_t)b * SEQ);
}

// ---------------------------------------------------------------------------
// K4: O[b] = (P'[b] @ V[b]) / rowsum, k-tiles to the causal diagonal, fp32 out.
__global__ __launch_bounds__(256) void pv_kernel(
    const __bf16* __restrict__ P, const __bf16* __restrict__ Vt,
    const float* __restrict__ sums, float* __restrict__ out)
{
    const int L = blockIdx.x;
    const int c = L & 7;
    const int k = L >> 3;                 // 0..63
    const int b = c >> 1;
    const int i = 15 - (c & 1) - ((k >> 3) << 1);   // 15,13,..,1 or 14,12,..,0
    const int x = k & 7;

    __shared__ __bf16 smem[8192];
    __bf16* lA = smem;
    __bf16* lB = smem + 128 * BK;
    const __bf16* A  = P  + (size_t)b * SEQ * SEQ;
    const __bf16* Bm = Vt + (size_t)b * DIM * SEQ;

    f32x4 acc[4][4];
    gemm_core(A, SEQ, Bm, SEQ, i << 7, x << 7, (i + 1) * (128 / BK), lA, lB, acc);

    const int lane = threadIdx.x & 63;
    const int wave = threadIdx.x >> 6;
    const int wm = (wave >> 1) << 6, wn = (wave & 1) << 6;
#pragma unroll
    for (int ii = 0; ii < 4; ++ii)
#pragma unroll
        for (int jj = 0; jj < 4; ++jj)
#pragma unroll
            for (int r = 0; r < 4; ++r) {
                const int m = (i << 7) + wm + ii * 16 + ((lane >> 4) << 2) + r;
                const int n = (x << 7) + wn + jj * 16 + (lane & 15);
                out[((size_t)b * SEQ + m) * DIM + n] =
                    acc[ii][jj][r] / sums[(b << 11) + m];
            }
}

// ---------------------------------------------------------------------------
extern "C" void kernel_launch(void* const* d_in, const int* in_sizes, int n_in,
                              void* d_out, int out_size, void* d_ws, size_t ws_size,
                              hipStream_t stream) {
    const float* x  = (const float*)d_in[0];   // fp32 per reference
    const float* Wq = (const float*)d_in[1];
    const float* Wk = (const float*)d_in[2];
    const float* Wv = (const float*)d_in[3];
    float* out = (float*)d_out;                // fp32 output (reference dtype)

    char* ws = (char*)d_ws;
    __bf16* Q  = (__bf16*)(ws);                       // 16 MB
    __bf16* Kb = (__bf16*)(ws + (16ull << 20));       // 16 MB
    __bf16* Vt = (__bf16*)(ws + (32ull << 20));       // 16 MB
    __bf16* Sc = (__bf16*)(ws + (48ull << 20));       // 32 MB bf16 exp-scores
    __bf16* Wqb = (__bf16*)(ws + (80ull << 20));      // 2 MB
    __bf16* Wkb = (__bf16*)(ws + (82ull << 20));      // 2 MB
    __bf16* Wvb = (__bf16*)(ws + (84ull << 20));      // 2 MB
    float*  sums = (float*)(ws + (86ull << 20));      // 32 KB row sums
    // bf16 x copy lives in d_out (32 MB fp32): dead before pv writes out.
    __bf16* xb  = (__bf16*)d_out;                     // 16 MB

    cvt_all_kernel<<<dim3(5640), 256, 0, stream>>>(x, Wq, Wk, Wv, xb, Wqb, Wkb, Wvb, sums);

    qkv_kernel    <<<dim3(256),  512, 0, stream>>>(xb, Wqb, Wkb, Wvb, Q, Kb, Vt);
    scores_kernel <<<dim3(544),  256, 0, stream>>>(Q, Kb, Sc, sums);
    pv_kernel     <<<dim3(512),  256, 0, stream>>>(Sc, Vt, sums, out);
}

// Round 6
// 221.372 us; speedup vs baseline: 1.0433x; 1.0433x over previous
//
#include <hip/hip_runtime.h>

// Problem constants
#define BATCH 4
#define SEQ   2048
#define DIM   1024
#define MTOT  (BATCH * SEQ)   // 8192
#define BK    32              // k-tile depth for the legacy 128x128 core

typedef __bf16 bf16x8 __attribute__((ext_vector_type(8)));
typedef __bf16 bf16x4 __attribute__((ext_vector_type(4)));
typedef float  f32x4  __attribute__((ext_vector_type(4)));

#define VMCNT(N) asm volatile("s_waitcnt vmcnt(" #N ")" ::: "memory")

// Async global->LDS, 16B per lane.
__device__ __forceinline__ void gl_lds16(const __bf16* g, __bf16* l) {
    __builtin_amdgcn_global_load_lds(
        (const __attribute__((address_space(1))) void*)g,
        (__attribute__((address_space(3))) void*)l,
        16, 0, 0);
}

// ---------------------------------------------------------------------------
// K0: fused fp32 -> bf16 conversion for x, Wq, Wk, Wv in ONE launch.
// Blocks 5632..5639 zero the row-sum accumulator (8192 f32).
// Blocks 5640..5671 zero the 32 above-diagonal 128x128 Sc tiles inside each
// diagonal 256-block (pv's 256-row units read them; scores never writes them).
__global__ __launch_bounds__(256) void cvt_all_kernel(
    const float* __restrict__ x,  const float* __restrict__ w0,
    const float* __restrict__ w1, const float* __restrict__ w2,
    __bf16* __restrict__ xd, __bf16* __restrict__ d0,
    __bf16* __restrict__ d1, __bf16* __restrict__ d2,
    float* __restrict__ sums, __bf16* __restrict__ Sc)
{
    const int bid = blockIdx.x;
    if (bid >= 5640) {
        const int t  = bid - 5640;            // 0..31
        const int bb = t >> 3, i2 = t & 7;
        __bf16* base = Sc + (size_t)bb * SEQ * SEQ
                          + (size_t)(i2 * 256) * SEQ + (i2 * 256 + 128);
        const bf16x8 z8 = {};
#pragma unroll
        for (int it = 0; it < 8; ++it) {
            const int row = it * 16 + (threadIdx.x >> 4);
            const int col = (threadIdx.x & 15) << 3;
            *(bf16x8*)(base + (size_t)row * SEQ + col) = z8;
        }
        return;
    }
    if (bid >= 5632) {
        const int i = ((bid - 5632) * 256 + threadIdx.x) * 4;
        *(float4*)(sums + i) = (float4){0.f, 0.f, 0.f, 0.f};
        return;
    }
    const float* s;
    __bf16* d;
    int base;
    if (bid < 4096)      { s = x;  d = xd; base = bid; }
    else if (bid < 4608) { s = w0; d = d0; base = bid - 4096; }
    else if (bid < 5120) { s = w1; d = d1; base = bid - 4608; }
    else                 { s = w2; d = d2; base = bid - 5120; }
    const int i = (base * 256 + threadIdx.x) * 8;
    const float4 a = *(const float4*)(s + i);
    const float4 b = *(const float4*)(s + i + 4);
    bf16x8 o;
    o[0] = (__bf16)a.x; o[1] = (__bf16)a.y; o[2] = (__bf16)a.z; o[3] = (__bf16)a.w;
    o[4] = (__bf16)b.x; o[5] = (__bf16)b.y; o[6] = (__bf16)b.z; o[7] = (__bf16)b.w;
    *(bf16x8*)(d + i) = o;
}

// ---------------------------------------------------------------------------
// Legacy 128x128 bf16 GEMM core (m97 structure) — still used by scores.
__device__ __forceinline__ void gemm_core(
    const __bf16* __restrict__ A, size_t lda,
    const __bf16* __restrict__ Bm, size_t ldb,
    int m0, int n0, int kTiles,
    __bf16* lA, __bf16* lB,
    f32x4 (&acc)[4][4])
{
    const int tid  = threadIdx.x;
    const int lane = tid & 63;
    const int wave = tid >> 6;
    const int wm = (wave >> 1) << 6;
    const int wn = (wave & 1) << 6;

#pragma unroll
    for (int i = 0; i < 4; ++i)
#pragma unroll
        for (int j = 0; j < 4; ++j)
            acc[i][j] = (f32x4){0.f, 0.f, 0.f, 0.f};

    for (int kt = 0; kt < kTiles; ++kt) {
        const int k0 = kt << 5;
        __syncthreads();
#pragma unroll
        for (int it = 0; it < 2; ++it) {
            const int f   = tid + (it << 8);
            const int row = f >> 2;
            const int col = (f & 3) << 3;
            gl_lds16(A  + (size_t)(m0 + row) * lda + (size_t)(k0 + col), lA + f * 8);
            gl_lds16(Bm + (size_t)(n0 + row) * ldb + (size_t)(k0 + col), lB + f * 8);
        }
        __syncthreads();

        bf16x8 af[4], bfr[4];
#pragma unroll
        for (int i = 0; i < 4; ++i) {
            af[i]  = *(const bf16x8*)(lA + (size_t)(wm + i * 16 + (lane & 15)) * BK + ((lane >> 4) << 3));
            bfr[i] = *(const bf16x8*)(lB + (size_t)(wn + i * 16 + (lane & 15)) * BK + ((lane >> 4) << 3));
        }
#pragma unroll
        for (int i = 0; i < 4; ++i)
#pragma unroll
            for (int j = 0; j < 4; ++j)
                acc[i][j] = __builtin_amdgcn_mfma_f32_16x16x32_bf16(af[i], bfr[j], acc[i][j], 0, 0, 0);
    }
}

// Epilogue for the legacy core (scores): C-tile -> LDS scratch -> coalesced
// bf16x8 stores. expMask: store exp(val*scale), causal-masked on diag tiles.
// sums!=nullptr: accumulate per-row sums of the STORED (bf16-rounded) values.
__device__ __forceinline__ void store_tile_bf16(
    f32x4 (&acc)[4][4], __bf16* scratch, bool transpose, float scale,
    __bf16* dst, size_t ldo, size_t r0, size_t c0,
    bool expMask = false, bool diag = false, float* sums = nullptr)
{
    const int tid  = threadIdx.x;
    const int lane = tid & 63;
    const int wave = tid >> 6;
    const int wm = (wave >> 1) << 6, wn = (wave & 1) << 6;
    const int quad = lane >> 4;
    const int ln15 = lane & 15;

#pragma unroll
    for (int p = 0; p < 4; ++p) {
        __syncthreads();
        if (!transpose) {
            if (wm == ((p >> 1) << 6)) {
#pragma unroll
                for (int ih = 0; ih < 2; ++ih) {
                    const int i = ((p & 1) << 1) + ih;
                    const int lr = ih * 16 + quad * 4;
#pragma unroll
                    for (int r = 0; r < 4; ++r) {
                        const int lm = wm + ((p & 1) << 5) + lr + r;
                        float ps = 0.f;
#pragma unroll
                        for (int j = 0; j < 4; ++j) {
                            const int ln = wn + j * 16 + ln15;
                            float v = acc[i][j][r] * scale;
                            if (expMask) {
                                v = (!diag || ln <= lm) ? __expf(v) : 0.f;
                            }
                            const __bf16 vb = (__bf16)v;
                            scratch[(lr + r) * 136 + ln] = vb;
                            ps += (float)vb;
                        }
                        if (sums) {
#pragma unroll
                            for (int off = 1; off < 16; off <<= 1)
                                ps += __shfl_xor(ps, off);
                            if (ln15 == 0)
                                atomicAdd(&sums[r0 + (p << 5) + lr + r], ps);
                        }
                    }
                }
            }
        } else {
            if (wn == ((p >> 1) << 6)) {
#pragma unroll
                for (int jh = 0; jh < 2; ++jh) {
                    const int j = ((p & 1) << 1) + jh;
                    const int lr = jh * 16 + ln15;
#pragma unroll
                    for (int i = 0; i < 4; ++i)
#pragma unroll
                        for (int r = 0; r < 4; ++r)
                            scratch[lr * 136 + wm + i * 16 + quad * 4 + r] =
                                (__bf16)(acc[i][j][r] * scale);
                }
            }
        }
        __syncthreads();
#pragma unroll
        for (int it = 0; it < 2; ++it) {
            const int g   = tid + (it << 8);
            const int row = g >> 4;
            const int col = (g & 15) << 3;
            *(bf16x8*)(dst + (r0 + p * 32 + row) * ldo + c0 + col) =
                *(const bf16x8*)(scratch + row * 136 + col);
        }
    }
}

// ---------------------------------------------------------------------------
// Shared 256x128 / BK=64 FAT-PHASE unit GEMM: C[256][128] = A[256][K]·B[128][K]^T.
// 512 threads, wave grid 4M x 2N, wave = 64x64, acc[i][j] frag (i,j) at
// rows wm*64+i*16+quad*4+r, cols wn*64+j*16+ln15.
// 2 phases per K-tile (16 MFMA/phase/wave, 4 barriers/tile):
//   P0: ds_read all aF (8) + bF0,bF1 (4) | stage B(T+1) [2] | VMCNT(2) seals
//       A(T+1) | bar | 16 MFMA (G0,G1) | bar
//   P1: ds_read bF2,bF3 (4) | stage A(T+2) [4] | VMCNT(4) seals B(T+1)
//       | bar | 16 MFMA (G2,G3) | bar
// Overwrite ledger: A(T+2)@P1 overwrites A(T), whose readers completed their
// lgkm-waited MFMAs before P0's closing barrier; B(T+1)@P0 overwrites B(T-1),
// read at P1(T-1) (2 barriers earlier). Tails: P1 with T+2>=nt -> VMCNT(0);
// last tile stages/seals nothing. Rotation swizzle (phys chunk =
// (log+row&7)&7): inverse on global source col, forward on ds_read col.
__device__ __forceinline__ void unit_gemm(
    const __bf16* __restrict__ Ab, size_t lda,
    const __bf16* __restrict__ Bb, size_t ldb,
    int nt, __bf16* smem, f32x4 (&acc)[4][4])
{
    const int tid  = threadIdx.x;
    const int lane = tid & 63;
    const int ln15 = lane & 15;
    const int quad = lane >> 4;
    const int wave = tid >> 6;
    const int wm   = wave >> 1;        // 0..3 (M)
    const int wn   = wave & 1;         // 0..1 (N)
    const int r0   = tid >> 3;                                   // 0..63
    const int cst  = ((((tid & 7) + 8) - (r0 & 7)) & 7) << 3;    // inv-rot col
    const int cq   = (((quad << 3) + ((ln15 & 7) << 3)) & 63);   // fwd-rot col

    int aoff[4], boff[4];
#pragma unroll
    for (int i = 0; i < 4; ++i) aoff[i] = ((wm << 6) + i * 16 + ln15) * 64 + cq;
#pragma unroll
    for (int j = 0; j < 4; ++j) boff[j] = 16384 + ((wn << 6) + j * 16 + ln15) * 64 + cq;

#pragma unroll
    for (int i = 0; i < 4; ++i)
#pragma unroll
        for (int j = 0; j < 4; ++j) acc[i][j] = (f32x4){0.f, 0.f, 0.f, 0.f};

    bf16x8 aF[4][2], bFr[2][2];

    // LDS per buf (elems): A[256][64]@0, B[128][64]@16384; buf stride 24576.
#define SA(h, t) do {                                                         \
    const __bf16* gs_ = Ab + (size_t)((h) * 128 + r0) * lda + ((t) << 6) + cst; \
    __bf16* ls_ = smem + (((t) & 1) * 24576 + (h) * 8192) + tid * 8;          \
    gl_lds16(gs_, ls_);                                                       \
    gl_lds16(gs_ + (size_t)64 * lda, ls_ + 4096); } while (0)
#define SB(h, t) do {                                                         \
    const __bf16* gs_ = Bb + (size_t)((h) * 64 + r0) * ldb + ((t) << 6) + cst; \
    __bf16* ls_ = smem + (((t) & 1) * 24576 + 16384 + (h) * 4096) + tid * 8;  \
    gl_lds16(gs_, ls_); } while (0)
#define LDA_ALL(t) do { const __bf16* p_ = smem + ((t) & 1) * 24576;          \
    _Pragma("unroll") for (int i_ = 0; i_ < 4; ++i_) {                        \
        aF[i_][0] = *(const bf16x8*)(p_ + aoff[i_]);                          \
        aF[i_][1] = *(const bf16x8*)(p_ + (aoff[i_] ^ 32)); } } while (0)
#define LDB2(s, j, t) do { const __bf16* p_ = smem + ((t) & 1) * 24576;       \
    bFr[s][0] = *(const bf16x8*)(p_ + boff[j]);                               \
    bFr[s][1] = *(const bf16x8*)(p_ + (boff[j] ^ 32)); } while (0)
#define MG(j, s) do {                                                         \
    _Pragma("unroll") for (int i_ = 0; i_ < 4; ++i_) {                        \
        acc[i_][j] = __builtin_amdgcn_mfma_f32_16x16x32_bf16(                 \
            aF[i_][0], bFr[s][0], acc[i_][j], 0, 0, 0);                       \
        acc[i_][j] = __builtin_amdgcn_mfma_f32_16x16x32_bf16(                 \
            aF[i_][1], bFr[s][1], acc[i_][j], 0, 0, 0); } } while (0)

    // Prologue: tile0 (6 insts) + A(1) (4 insts); seal tile0 (leave A(1) out).
    SA(0, 0); SA(1, 0); SB(0, 0); SB(1, 0);
    SA(0, 1); SA(1, 1);
    VMCNT(4);
    __builtin_amdgcn_s_barrier();

    for (int T = 0; T < nt; ++T) {
        // ---- P0 ----
        LDA_ALL(T);
        LDB2(0, 0, T); LDB2(1, 1, T);
        if (T + 1 < nt) {
            SB(0, T + 1); SB(1, T + 1);
            VMCNT(2);                      // A(T+1) landed (B(T+1) in flight)
        }
        __builtin_amdgcn_s_barrier();
        __builtin_amdgcn_s_setprio(1);
        MG(0, 0); MG(1, 1);
        __builtin_amdgcn_s_setprio(0);
        __builtin_amdgcn_s_barrier();
        // ---- P1 ----
        LDB2(0, 2, T); LDB2(1, 3, T);
        if (T + 2 < nt) {
            SA(0, T + 2); SA(1, T + 2);
            VMCNT(4);                      // B(T+1) landed (A(T+2) in flight)
        } else if (T + 1 < nt) {
            VMCNT(0);                      // drain B(T+1)
        }
        __builtin_amdgcn_s_barrier();
        __builtin_amdgcn_s_setprio(1);
        MG(2, 0); MG(3, 1);
        __builtin_amdgcn_s_setprio(0);
        __builtin_amdgcn_s_barrier();
    }
#undef SA
#undef SB
#undef LDA_ALL
#undef LDB2
#undef MG
}

// ---------------------------------------------------------------------------
// K1: QKV — 256 blocks x 3 sequential 256x128 units (shared A-panel), each
// unit via the fat-phase unit_gemm. Epilogue identical to round 3.
__global__ __launch_bounds__(512, 2) void qkv_kernel(
    const __bf16* __restrict__ x,
    const __bf16* __restrict__ Wq,
    const __bf16* __restrict__ Wk,
    const __bf16* __restrict__ Wv,
    __bf16* __restrict__ Q, __bf16* __restrict__ Kb, __bf16* __restrict__ Vt)
{
    __shared__ __bf16 smem[49152];   // 96 KiB

    const int L  = blockIdx.x;
    const int g  = (L & 7) * 32 + (L >> 3);   // bijective XCD swizzle (256=8*32)
    const int m0 = (g >> 3) << 8;             // 32 m-panels of 256 rows
    const int B3 = g & 7;                     // unit-triple within the panel

    const int tid  = threadIdx.x;
    const int lane = tid & 63;
    const int ln15 = lane & 15;
    const int quad = lane >> 4;
    const int wave = tid >> 6;
    const int wm   = wave >> 1;        // 0..3 (M)
    const int wn   = wave & 1;         // 0..1 (N)

    const __bf16* Ab = x + (size_t)m0 * DIM;

    for (int uu = 0; uu < 3; ++uu) {
        const int u  = B3 * 3 + uu;
        const int z  = u >> 3;             // 0=Q, 1=K, 2=V
        const int n0 = (u & 7) << 7;
        const __bf16* W  = (z == 0) ? Wq : (z == 1) ? Wk : Wv;

        f32x4 acc[4][4];
        unit_gemm(Ab, DIM, W + (size_t)n0 * DIM, DIM, DIM / 64, smem, acc);

        // ---------------- epilogue ----------------
        __syncthreads();
        __bf16* scratch = smem;

        if (z < 2) {
            __bf16* dst = (z == 0) ? Q : Kb;
#pragma unroll
            for (int h = 0; h < 2; ++h) {     // slab: C rows h*128..h*128+127
                if ((wm >> 1) == h) {
#pragma unroll
                    for (int i = 0; i < 4; ++i) {
                        const int lr = ((wm & 1) << 6) + i * 16 + quad * 4;
#pragma unroll
                        for (int j = 0; j < 4; ++j) {
                            const int lc = (wn << 6) + j * 16 + ln15;
#pragma unroll
                            for (int r = 0; r < 4; ++r)
                                scratch[(lr + r) * 136 + lc] = (__bf16)acc[i][j][r];
                        }
                    }
                }
                __syncthreads();
#pragma unroll
                for (int it = 0; it < 4; ++it) {
                    const int f = tid + (it << 9);
                    const int row = f >> 4, col = (f & 15) << 3;
                    *(bf16x8*)(dst + (size_t)(m0 + h * 128 + row) * DIM + n0 + col) =
                        *(const bf16x8*)(scratch + row * 136 + col);
                }
                __syncthreads();
            }
        } else {
            // V transposed: Vt[b][d][s]; scratch[d 128][s 256], stride 264.
            const size_t b  = (size_t)(m0 >> 11);
            const int  ms0  = m0 & (SEQ - 1);
            __bf16* dst = Vt + b * (size_t)DIM * SEQ;
#pragma unroll
            for (int i = 0; i < 4; ++i) {
                const int sl = (wm << 6) + i * 16 + quad * 4;   // s-local 0..255
#pragma unroll
                for (int j = 0; j < 4; ++j) {
                    const int dl = (wn << 6) + j * 16 + ln15;    // d-local 0..127
                    bf16x4 v;
#pragma unroll
                    for (int r = 0; r < 4; ++r) v[r] = (__bf16)acc[i][j][r];
                    *(bf16x4*)(scratch + dl * 264 + sl) = v;
                }
            }
            __syncthreads();
#pragma unroll
            for (int it = 0; it < 8; ++it) {
                const int f = tid + (it << 9);
                const int row = f >> 5, blk = f & 31;
                *(bf16x8*)(dst + (size_t)(n0 + row) * SEQ + ms0 + blk * 8) =
                    *(const bf16x8*)(scratch + row * 264 + blk * 8);
            }
            __syncthreads();
        }
    }
}

// ---------------------------------------------------------------------------
// K2: Sc[b] = exp( Q[b]·K[b]^T / 32 ), UNNORMALIZED, causal-masked on the
// diagonal tile; accumulates per-row sums. Tri-packed 544 blocks; XCD swizzle.
__global__ __launch_bounds__(256) void scores_kernel(
    const __bf16* __restrict__ Q, const __bf16* __restrict__ Kb,
    __bf16* __restrict__ Sc, float* __restrict__ sums)
{
    const int L = blockIdx.x;
    const int g = (L & 7) * 68 + (L >> 3);   // 0..543
    const int b = g / 136;
    const int t = g - b * 136;
    int i = (int)((sqrtf(8.f * t + 1.f) - 1.f) * 0.5f);
    while ((i + 1) * (i + 2) / 2 <= t) ++i;
    while (i * (i + 1) / 2 > t) --i;
    const int j = t - i * (i + 1) / 2;

    __shared__ __bf16 smem[8192];
    __bf16* lA = smem;
    __bf16* lB = smem + 128 * BK;
    const __bf16* A  = Q  + (size_t)b * SEQ * DIM;
    const __bf16* Bm = Kb + (size_t)b * SEQ * DIM;

    f32x4 acc[4][4];
    gemm_core(A, DIM, Bm, DIM, i << 7, j << 7, DIM / BK, lA, lB, acc);

    store_tile_bf16(acc, smem, false, 0.03125f,   // 1/sqrt(1024)
                    Sc + (size_t)b * SEQ * SEQ, SEQ,
                    (size_t)(i << 7), (size_t)(j << 7),
                    /*expMask=*/true, /*diag=*/(i == j),
                    sums + (size_t)b * SEQ);
}

// ---------------------------------------------------------------------------
// K4: O[b] = (P'[b] @ V[b]) / rowsum via the fat-phase unit machine.
// 256 blocks EXACT: unit = 256 P-rows x 128 V-cols, kTiles=(i2+1)*4 (BK=64,
// K to the causal diagonal 256-block; above-diag 128-tiles are zero-filled).
// XCD c owns batch c>>1 with alternating-i2 set, i2-descending (LPT).
__global__ __launch_bounds__(512, 2) void pv_kernel(
    const __bf16* __restrict__ P, const __bf16* __restrict__ Vt,
    const float* __restrict__ sums, float* __restrict__ out)
{
    __shared__ __bf16 smem[49152];   // 96 KiB

    const int L  = blockIdx.x;
    const int c  = L & 7;
    const int k  = L >> 3;                         // 0..31
    const int b  = c >> 1;
    const int i2 = 7 - (c & 1) - ((k >> 3) << 1);  // {7,5,3,1} or {6,4,2,0}
    const int xx = k & 7;

    const __bf16* Ab = P  + (size_t)b * SEQ * SEQ + (size_t)(i2 << 8) * SEQ;
    const __bf16* Bb = Vt + (size_t)b * DIM * SEQ + (size_t)(xx << 7) * SEQ;

    f32x4 acc[4][4];
    unit_gemm(Ab, SEQ, Bb, SEQ, (i2 + 1) << 2, smem, acc);

    const int tid  = threadIdx.x;
    const int lane = tid & 63;
    const int ln15 = lane & 15;
    const int quad = lane >> 4;
    const int wave = tid >> 6;
    const int wm   = wave >> 1;
    const int wn   = wave & 1;

#pragma unroll
    for (int i = 0; i < 4; ++i)
#pragma unroll
        for (int r = 0; r < 4; ++r) {
            const int m = (i2 << 8) + (wm << 6) + i * 16 + quad * 4 + r;
            const float s = sums[(b << 11) + m];
            float* orow = out + ((size_t)b * SEQ + m) * DIM + (xx << 7);
#pragma unroll
            for (int j = 0; j < 4; ++j)
                orow[(wn << 6) + j * 16 + ln15] = acc[i][j][r] / s;
        }
}

// ---------------------------------------------------------------------------
extern "C" void kernel_launch(void* const* d_in, const int* in_sizes, int n_in,
                              void* d_out, int out_size, void* d_ws, size_t ws_size,
                              hipStream_t stream) {
    const float* x  = (const float*)d_in[0];   // fp32 per reference
    const float* Wq = (const float*)d_in[1];
    const float* Wk = (const float*)d_in[2];
    const float* Wv = (const float*)d_in[3];
    float* out = (float*)d_out;                // fp32 output (reference dtype)

    char* ws = (char*)d_ws;
    __bf16* Q  = (__bf16*)(ws);                       // 16 MB
    __bf16* Kb = (__bf16*)(ws + (16ull << 20));       // 16 MB
    __bf16* Vt = (__bf16*)(ws + (32ull << 20));       // 16 MB
    __bf16* Sc = (__bf16*)(ws + (48ull << 20));       // 32 MB bf16 exp-scores
    __bf16* Wqb = (__bf16*)(ws + (80ull << 20));      // 2 MB
    __bf16* Wkb = (__bf16*)(ws + (82ull << 20));      // 2 MB
    __bf16* Wvb = (__bf16*)(ws + (84ull << 20));      // 2 MB
    float*  sums = (float*)(ws + (86ull << 20));      // 32 KB row sums
    // bf16 x copy lives in d_out (32 MB fp32): dead before pv writes out.
    __bf16* xb  = (__bf16*)d_out;                     // 16 MB

    cvt_all_kernel<<<dim3(5672), 256, 0, stream>>>(x, Wq, Wk, Wv, xb, Wqb, Wkb, Wvb,
                                                   sums, Sc);

    qkv_kernel    <<<dim3(256),  512, 0, stream>>>(xb, Wqb, Wkb, Wvb, Q, Kb, Vt);
    scores_kernel <<<dim3(544),  256, 0, stream>>>(Q, Kb, Sc, sums);
    pv_kernel     <<<dim3(256),  512, 0, stream>>>(Sc, Vt, sums, out);
}

// Round 9
// 211.033 us; speedup vs baseline: 1.0944x; 1.0490x over previous
//
#include <hip/hip_runtime.h>

// Problem constants
#define BATCH 4
#define SEQ   2048
#define DIM   1024
#define MTOT  (BATCH * SEQ)   // 8192

typedef __bf16 bf16x8 __attribute__((ext_vector_type(8)));
typedef float  f32x4  __attribute__((ext_vector_type(4)));

#define VMCNT(N) asm volatile("s_waitcnt vmcnt(" #N ")" ::: "memory")

// Async global->LDS, 16B per lane (HW: wave-uniform base + lane*16).
__device__ __forceinline__ void gl_lds16(const __bf16* g, __bf16* l) {
    __builtin_amdgcn_global_load_lds(
        (const __attribute__((address_space(1))) void*)g,
        (__attribute__((address_space(3))) void*)l,
        16, 0, 0);
}

// ---------------------------------------------------------------------------
// K0: fused fp32 -> bf16 conversion for x, Wq, Wk, Wv in ONE launch.
// Blocks 5632..5639 zero the row-sum accumulator (8192 f32).
__global__ __launch_bounds__(256) void cvt_all_kernel(
    const float* __restrict__ x,  const float* __restrict__ w0,
    const float* __restrict__ w1, const float* __restrict__ w2,
    __bf16* __restrict__ xd, __bf16* __restrict__ d0,
    __bf16* __restrict__ d1, __bf16* __restrict__ d2,
    float* __restrict__ sums)
{
    const int bid = blockIdx.x;
    if (bid >= 5632) {
        const int i = ((bid - 5632) * 256 + threadIdx.x) * 4;
        *(float4*)(sums + i) = (float4){0.f, 0.f, 0.f, 0.f};
        return;
    }
    const float* s;
    __bf16* d;
    int base;
    if (bid < 4096)      { s = x;  d = xd; base = bid; }
    else if (bid < 4608) { s = w0; d = d0; base = bid - 4096; }
    else if (bid < 5120) { s = w1; d = d1; base = bid - 4608; }
    else                 { s = w2; d = d2; base = bid - 5120; }
    const int i = (base * 256 + threadIdx.x) * 8;
    const float4 a = *(const float4*)(s + i);
    const float4 b = *(const float4*)(s + i + 4);
    bf16x8 o;
    o[0] = (__bf16)a.x; o[1] = (__bf16)a.y; o[2] = (__bf16)a.z; o[3] = (__bf16)a.w;
    o[4] = (__bf16)b.x; o[5] = (__bf16)b.y; o[6] = (__bf16)b.z; o[7] = (__bf16)b.w;
    *(bf16x8*)(d + i) = o;
}

// ---------------------------------------------------------------------------
// unit128: C[128][128] = A[128][K]·B[128][K]^T, BK=64, 256 threads (4 waves),
// wave grid 2M x 2N (wave 64x64, acc[4][4], legacy fragment mapping:
// rows wm + i*16 + quad*4 + r, cols wn + j*16 + ln15).
// LDS 64 KiB: dbuf x (A[128][64] @0 + B[128][64] @8192 elems); with 256-thr
// blocks this gives 2 blocks/CU (8 waves) — co-resident blocks overlap
// MFMA and LDS phases across independent barrier domains (m114).
// One fat phase per K-tile:
//   STG(T+1): 8 gl_lds (4 A + 4 B) into buf[(T+1)&1]   [dead since T-1]
//   VMCNT(8): counted seal — tile T's 8 stages retired, T+1's stay in
//             flight ACROSS the barrier (m218 counted-vmcnt lever)
//   barrier; 16 ds_read_b128 (aF+bF); [compiler lgkm]; 32 MFMA; barrier.
// Rotation swizzle: LDS[r][lc] holds G[r][(lc - r) & 7] (8-elem chunks);
// inverse rotation on the gl_lds global source column, forward rotation on
// the ds_read address; ksub1 = ksub0 address ^ 32 elems (+4 mod 8 chunks).
__device__ __forceinline__ void unit128(
    const __bf16* __restrict__ Ab, size_t lda,
    const __bf16* __restrict__ Bb, size_t ldb,
    int nt, __bf16* smem, f32x4 (&acc)[4][4])
{
    const int tid  = threadIdx.x;           // 0..255
    const int lane = tid & 63;
    const int ln15 = lane & 15;
    const int quad = lane >> 4;
    const int wave = tid >> 6;              // 0..3
    const int wm   = (wave >> 1) << 6;      // 0 / 64
    const int wn   = (wave & 1) << 6;       // 0 / 64

    // forward-rotated read column (elements): chunk = (quad + row&7) & 7
    const int cq = (((quad << 3) + ((ln15 & 7) << 3)) & 63);

    int aoff[4], boff[4];
#pragma unroll
    for (int i = 0; i < 4; ++i) aoff[i] = (wm + i * 16 + ln15) * 64 + cq;
#pragma unroll
    for (int j = 0; j < 4; ++j) boff[j] = 8192 + (wn + j * 16 + ln15) * 64 + cq;

#pragma unroll
    for (int i = 0; i < 4; ++i)
#pragma unroll
        for (int j = 0; j < 4; ++j) acc[i][j] = (f32x4){0.f, 0.f, 0.f, 0.f};

    // Stage tile t: thread covers chunks c = tid + it*256 (row=c>>3, lc=c&7);
    // source column chunk = (lc - row) & 7 (inverse rotation); dest linear.
#define STG(t) do {                                                           \
    const int k0_ = (t) << 6;                                                 \
    __bf16* lb_ = smem + (((t) & 1) << 14);                                   \
    _Pragma("unroll") for (int it_ = 0; it_ < 4; ++it_) {                     \
        const int c_ = tid + (it_ << 8);                                      \
        const int r_ = c_ >> 3;                                               \
        const int cc_ = ((((c_ & 7) + 8) - (r_ & 7)) & 7) << 3;               \
        gl_lds16(Ab + (size_t)r_ * lda + k0_ + cc_, lb_ + c_ * 8);            \
        gl_lds16(Bb + (size_t)r_ * ldb + k0_ + cc_, lb_ + 8192 + c_ * 8);     \
    } } while (0)

    bf16x8 aF[4][2], bF[4][2];

    STG(0);                                  // prologue: tile 0 in flight (8)

    for (int T = 0; T < nt; ++T) {
        const __bf16* rb = smem + ((T & 1) << 14);
        if (T + 1 < nt) {
            STG(T + 1);                      // outstanding: T's 8 + T+1's 8
            VMCNT(8);                        // tile T sealed, T+1 in flight
        } else {
            VMCNT(0);                        // tail: seal last tile
        }
        __builtin_amdgcn_s_barrier();
#pragma unroll
        for (int i = 0; i < 4; ++i) {
            aF[i][0] = *(const bf16x8*)(rb + aoff[i]);
            aF[i][1] = *(const bf16x8*)(rb + (aoff[i] ^ 32));
        }
#pragma unroll
        for (int j = 0; j < 4; ++j) {
            bF[j][0] = *(const bf16x8*)(rb + boff[j]);
            bF[j][1] = *(const bf16x8*)(rb + (boff[j] ^ 32));
        }
        __builtin_amdgcn_s_setprio(1);
#pragma unroll
        for (int ks = 0; ks < 2; ++ks)
#pragma unroll
            for (int i = 0; i < 4; ++i)
#pragma unroll
                for (int j = 0; j < 4; ++j)
                    acc[i][j] = __builtin_amdgcn_mfma_f32_16x16x32_bf16(
                        aF[i][ks], bF[j][ks], acc[i][j], 0, 0, 0);
        __builtin_amdgcn_s_setprio(0);
        __builtin_amdgcn_s_barrier();        // protect next STG of buf[T&1]
    }
#undef STG
}

// ---------------------------------------------------------------------------
// Epilogue (256-thr, 4-wave, legacy mapping): C-tile -> LDS scratch ->
// coalesced bf16x8 stores. expMask: store exp(val*scale), causal-masked on
// diag tiles. sums!=nullptr: per-row sums of stored (bf16-rounded) values.
__device__ __forceinline__ void store_tile_bf16(
    f32x4 (&acc)[4][4], __bf16* scratch, bool transpose, float scale,
    __bf16* dst, size_t ldo, size_t r0, size_t c0,
    bool expMask = false, bool diag = false, float* sums = nullptr)
{
    const int tid  = threadIdx.x;
    const int lane = tid & 63;
    const int wave = tid >> 6;
    const int wm = (wave >> 1) << 6, wn = (wave & 1) << 6;
    const int quad = lane >> 4;
    const int ln15 = lane & 15;

#pragma unroll
    for (int p = 0; p < 4; ++p) {
        __syncthreads();
        if (!transpose) {
            if (wm == ((p >> 1) << 6)) {
#pragma unroll
                for (int ih = 0; ih < 2; ++ih) {
                    const int i = ((p & 1) << 1) + ih;
                    const int lr = ih * 16 + quad * 4;
#pragma unroll
                    for (int r = 0; r < 4; ++r) {
                        const int lm = wm + ((p & 1) << 5) + lr + r;
                        float ps = 0.f;
#pragma unroll
                        for (int j = 0; j < 4; ++j) {
                            const int ln = wn + j * 16 + ln15;
                            float v = acc[i][j][r] * scale;
                            if (expMask) {
                                v = (!diag || ln <= lm) ? __expf(v) : 0.f;
                            }
                            const __bf16 vb = (__bf16)v;
                            scratch[(lr + r) * 136 + ln] = vb;
                            ps += (float)vb;
                        }
                        if (sums) {
#pragma unroll
                            for (int off = 1; off < 16; off <<= 1)
                                ps += __shfl_xor(ps, off);
                            if (ln15 == 0)
                                atomicAdd(&sums[r0 + (p << 5) + lr + r], ps);
                        }
                    }
                }
            }
        } else {
            if (wn == ((p >> 1) << 6)) {
#pragma unroll
                for (int jh = 0; jh < 2; ++jh) {
                    const int j = ((p & 1) << 1) + jh;
                    const int lr = jh * 16 + ln15;
#pragma unroll
                    for (int i = 0; i < 4; ++i)
#pragma unroll
                        for (int r = 0; r < 4; ++r)
                            scratch[lr * 136 + wm + i * 16 + quad * 4 + r] =
                                (__bf16)(acc[i][j][r] * scale);
                }
            }
        }
        __syncthreads();
#pragma unroll
        for (int it = 0; it < 2; ++it) {
            const int g   = tid + (it << 8);
            const int row = g >> 4;
            const int col = (g & 15) << 3;
            *(bf16x8*)(dst + (r0 + p * 32 + row) * ldo + c0 + col) =
                *(const bf16x8*)(scratch + row * 136 + col);
        }
    }
}

// ---------------------------------------------------------------------------
// K1: QKV — 512 blocks x 3 sequential 128x128 units (shared 128-row A-panel).
// Wall = contiguous [3072][1024] bf16 (Wqb|Wkb|Wvb adjacent in workspace).
// Exact 1 dispatch round at 2 blocks/CU. Bijective XCD swizzle (512 = 8*64).
__global__ __launch_bounds__(256, 2) void qkv_kernel(
    const __bf16* __restrict__ x,
    const __bf16* __restrict__ Wall,
    __bf16* __restrict__ Q, __bf16* __restrict__ Kb, __bf16* __restrict__ Vt)
{
    __shared__ __bf16 smem[32768];   // 64 KiB

    const int L  = blockIdx.x;
    const int g  = (L & 7) * 64 + (L >> 3);
    const int m0 = (g >> 3) << 7;      // 64 m-panels of 128 rows
    const int B3 = g & 7;

    const __bf16* Ab = x + (size_t)m0 * DIM;

    for (int uu = 0; uu < 3; ++uu) {
        const int u = B3 * 3 + uu;        // 0..23 over Wall's 3072 rows
        f32x4 acc[4][4];
        unit128(Ab, DIM, Wall + (size_t)(u << 7) * DIM, DIM, DIM / 64,
                smem, acc);

        const int z  = u >> 3;            // 0=Q, 1=K, 2=V
        const int n0 = (u & 7) << 7;
        if (z == 0) {
            store_tile_bf16(acc, smem, false, 1.f, Q,  DIM, m0, n0);
        } else if (z == 1) {
            store_tile_bf16(acc, smem, false, 1.f, Kb, DIM, m0, n0);
        } else {
            const size_t b  = (size_t)(m0 >> 11);
            const int  ms0  = m0 & (SEQ - 1);
            store_tile_bf16(acc, smem, true, 1.f,
                            Vt + b * (size_t)DIM * SEQ, SEQ, n0, ms0);
        }
        __syncthreads();
    }
}

// ---------------------------------------------------------------------------
// K2: Sc[b] = exp( Q[b]·K[b]^T / 32 ), UNNORMALIZED, causal-masked on the
// diagonal tile; accumulates per-row sums. Tri-packed 544 blocks; XCD swizzle.
__global__ __launch_bounds__(256, 2) void scores_kernel(
    const __bf16* __restrict__ Q, const __bf16* __restrict__ Kb,
    __bf16* __restrict__ Sc, float* __restrict__ sums)
{
    __shared__ __bf16 smem[32768];   // 64 KiB

    const int L = blockIdx.x;
    const int g = (L & 7) * 68 + (L >> 3);   // 0..543
    const int b = g / 136;
    const int t = g - b * 136;
    int i = (int)((sqrtf(8.f * t + 1.f) - 1.f) * 0.5f);
    while ((i + 1) * (i + 2) / 2 <= t) ++i;
    while (i * (i + 1) / 2 > t) --i;
    const int j = t - i * (i + 1) / 2;

    const __bf16* A  = Q  + (size_t)b * SEQ * DIM + (size_t)(i << 7) * DIM;
    const __bf16* Bm = Kb + (size_t)b * SEQ * DIM + (size_t)(j << 7) * DIM;

    f32x4 acc[4][4];
    unit128(A, DIM, Bm, DIM, DIM / 64, smem, acc);

    store_tile_bf16(acc, smem, false, 0.03125f,   // 1/sqrt(1024)
                    Sc + (size_t)b * SEQ * SEQ, SEQ,
                    (size_t)(i << 7), (size_t)(j << 7),
                    /*expMask=*/true, /*diag=*/(i == j),
                    sums + (size_t)b * SEQ);
}

// ---------------------------------------------------------------------------
// K4: O[b] = (P'[b] @ V[b]) / rowsum. 512 blocks (exact 1 round at 2/CU):
// unit = 128 P-rows (ti) x 128 V-cols (dj), K = (ti+1)*128 to the causal
// diagonal (tiles above diagonal never read). XCD c owns batch c>>1 with
// alternating-ti set, ti-descending (LPT).
__global__ __launch_bounds__(256, 2) void pv_kernel(
    const __bf16* __restrict__ P, const __bf16* __restrict__ Vt,
    const float* __restrict__ sums, float* __restrict__ out)
{
    __shared__ __bf16 smem[32768];   // 64 KiB

    const int L   = blockIdx.x;
    const int c   = L & 7;
    const int idx = L >> 3;                        // 0..63
    const int b   = c >> 1;
    const int ti  = 15 - (c & 1) - ((idx >> 3) << 1);  // {15,13,..,1}/{14,..,0}
    const int dj  = idx & 7;

    const __bf16* A  = P  + (size_t)b * SEQ * SEQ + (size_t)(ti << 7) * SEQ;
    const __bf16* Bm = Vt + (size_t)b * DIM * SEQ + (size_t)(dj << 7) * SEQ;

    f32x4 acc[4][4];
    unit128(A, SEQ, Bm, SEQ, (ti + 1) * 2, smem, acc);

    const int tid  = threadIdx.x;
    const int lane = tid & 63;
    const int ln15 = lane & 15;
    const int quad = lane >> 4;
    const int wave = tid >> 6;
    const int wm   = (wave >> 1) << 6;
    const int wn   = (wave & 1) << 6;

#pragma unroll
    for (int i = 0; i < 4; ++i)
#pragma unroll
        for (int r = 0; r < 4; ++r) {
            const int m = (ti << 7) + wm + i * 16 + quad * 4 + r;
            const float s = sums[(b << 11) + m];
            float* orow = out + ((size_t)b * SEQ + m) * DIM + (dj << 7);
#pragma unroll
            for (int j = 0; j < 4; ++j)
                orow[wn + j * 16 + ln15] = acc[i][j][r] / s;
        }
}

// ---------------------------------------------------------------------------
extern "C" void kernel_launch(void* const* d_in, const int* in_sizes, int n_in,
                              void* d_out, int out_size, void* d_ws, size_t ws_size,
                              hipStream_t stream) {
    const float* x  = (const float*)d_in[0];   // fp32 per reference
    const float* Wq = (const float*)d_in[1];
    const float* Wk = (const float*)d_in[2];
    const float* Wv = (const float*)d_in[3];
    float* out = (float*)d_out;                // fp32 output (reference dtype)

    char* ws = (char*)d_ws;
    __bf16* Q  = (__bf16*)(ws);                       // 16 MB
    __bf16* Kb = (__bf16*)(ws + (16ull << 20));       // 16 MB
    __bf16* Vt = (__bf16*)(ws + (32ull << 20));       // 16 MB
    __bf16* Sc = (__bf16*)(ws + (48ull << 20));       // 32 MB bf16 exp-scores
    __bf16* Wqb = (__bf16*)(ws + (80ull << 20));      // 2 MB (Wall rows 0..1023)
    __bf16* Wkb = (__bf16*)(ws + (82ull << 20));      // 2 MB (Wall rows 1024..2047)
    __bf16* Wvb = (__bf16*)(ws + (84ull << 20));      // 2 MB (Wall rows 2048..3071)
    float*  sums = (float*)(ws + (86ull << 20));      // 32 KB row sums
    // bf16 x copy lives in d_out (32 MB fp32): dead before pv writes out.
    __bf16* xb  = (__bf16*)d_out;                     // 16 MB

    cvt_all_kernel<<<dim3(5640), 256, 0, stream>>>(x, Wq, Wk, Wv, xb, Wqb, Wkb, Wvb,
                                                   sums);

    qkv_kernel    <<<dim3(512),  256, 0, stream>>>(xb, Wqb, Q, Kb, Vt);
    scores_kernel <<<dim3(544),  256, 0, stream>>>(Q, Kb, Sc, sums);
    pv_kernel     <<<dim3(512),  256, 0, stream>>>(Sc, Vt, sums, out);
}